// Round 17
// baseline (67.842 us; speedup 1.0000x reference)
//
#include <hip/hip_runtime.h>
#include <hip/hip_bf16.h>

#define IMG_H 320
#define IMG_W 320
#define NPIX (IMG_H * IMG_W)
#define HID 64
#define NS 32
#define ITER 4   // pixel-octets per block (round-12/16 best config)

typedef __attribute__((ext_vector_type(8))) short short8;   // bf16 x8 (4 VGPR)
typedef __attribute__((ext_vector_type(4))) float float4v;
typedef __attribute__((ext_vector_type(4))) int   int4v;

// ws layout (shorts): w2t[4096] | w1t[2048] | w3t[1024] ; floats: b3pad[16] | b2[64] | zpad
#define W2T_OFF 0
#define W1T_OFF 4096
#define W3T_OFF (4096 + 2048)
#define B3P_FLT 3584            // float index of b3pad (byte 14336)
#define B2_FLT  3600            // float index of b2 copy (byte 14400)
#define WS_BYTES 15360
#define PREP_BLOCKS 8

__device__ __forceinline__ unsigned f2bf(float f) {   // prep kernel only (cold)
    __hip_bfloat16 b = __float2bfloat16(f);
    return (unsigned)*reinterpret_cast<unsigned short*>(&b);
}

// HW packed f32->bf16 (RNE): lo16 = bf16(lo), hi16 = bf16(hi). One VALU op.
__device__ __forceinline__ unsigned cvtpk(float lo, float hi) {
    unsigned r;
    asm("v_cvt_pk_bf16_f32 %0, %1, %2" : "=v"(r) : "v"(lo), "v"(hi));
    return r;
}

// Volatile (non-hoistable) LDS reads WITHOUT embedded waits. Round 8-16
// postmortem: occupancy is pinned at ~11 waves/CU by PEAK-LIVE register
// footprint (~190/wave incl. all weight fragments resident all kernel).
// Making the small fragments transient (re-read per nt, live only within
// the nt body) cuts peak-live ~45 regs -> ~3.5 waves/SIMD. volatile asm
// guarantees the loads stay IN the loop (lifetime shape is forced).
// RULE-18: results are NOT valid until the LGKM_WAIT() fence below; every
// use must come after it in program order.
__device__ __forceinline__ short8 ldsr16nw(const short* p) {
    short8 r;
    asm volatile("ds_read_b128 %0, %1"
                 : "=v"(r)
                 : "v"((__attribute__((address_space(3))) const short*)p));
    return r;
}
__device__ __forceinline__ float4v ldsr16fnw(const float* p) {
    float4v r;
    asm volatile("ds_read_b128 %0, %1"
                 : "=v"(r)
                 : "v"((__attribute__((address_space(3))) const float*)p));
    return r;
}
// wait for all outstanding LDS ops + pin scheduling (no MFMA hoists above)
#define LGKM_WAIT()                                          \
    do {                                                     \
        asm volatile("s_waitcnt lgkmcnt(0)" ::: "memory");   \
        __builtin_amdgcn_sched_barrier(0);                   \
    } while (0)

// relu + pack two D-fragments (lo-half, hi-half) into the next layer's B-fragment.
__device__ __forceinline__ short8 packfrag(float4v lo, float4v hi) {
    int4v p;
    p[0] = (int)cvtpk(fmaxf(lo[0], 0.f), fmaxf(lo[1], 0.f));
    p[1] = (int)cvtpk(fmaxf(lo[2], 0.f), fmaxf(lo[3], 0.f));
    p[2] = (int)cvtpk(fmaxf(hi[0], 0.f), fmaxf(hi[1], 0.f));
    p[3] = (int)cvtpk(fmaxf(hi[2], 0.f), fmaxf(hi[3], 0.f));
    return *reinterpret_cast<short8*>(&p);
}

// DPP add helper + 32-lane inclusive scan (pure VALU, no LDS)
template <int CTRL, int RMASK>
__device__ __forceinline__ float dppadd(float x) {
    int s = __builtin_amdgcn_update_dpp(0, __float_as_int(x), CTRL, RMASK, 0xF, true);
    return x + __int_as_float(s);
}
__device__ __forceinline__ float scan32(float x) {
    x = dppadd<0x111, 0xF>(x);   // row_shr:1
    x = dppadd<0x112, 0xF>(x);   // row_shr:2
    x = dppadd<0x114, 0xF>(x);   // row_shr:4
    x = dppadd<0x118, 0xF>(x);   // row_shr:8
    x = dppadd<0x142, 0xA>(x);   // row_bcast:15 into rows 1,3
    return x;
}

// async global->LDS, 16B per lane (dest = uniform base + lane*16)
__device__ __forceinline__ void gload_lds16(const void* g, void* l) {
    __builtin_amdgcn_global_load_lds(
        (const __attribute__((address_space(1))) unsigned int*)g,
        (__attribute__((address_space(3))) unsigned int*)l, 16, 0, 0);
}

// Layout-fused weight tables (round-8 permutation for w1t/w2t; w3t rows
// replicated so every lane group receives the full raw quad -> register-only
// routing, race-free ITER loop).
__global__ __launch_bounds__(256) void prep(const float* __restrict__ W1,
                                            const float* __restrict__ b1,
                                            const float* __restrict__ W2,
                                            const float* __restrict__ W3,
                                            const float* __restrict__ b3,
                                            const float* __restrict__ b2,
                                            short* __restrict__ wsS) {
    int t = blockIdx.x * 256 + threadIdx.x;
    const int STR = 256 * PREP_BLOCKS;
    float* wsF = reinterpret_cast<float*>(wsS);
    for (int i = t; i < 4096; i += STR) {          // w2t
        int idx = i >> 9, m = (i >> 5) & 15, k2 = i & 31;
        int j3 = 32 * (idx >> 2) + 8 * (m >> 2) + 4 * ((idx >> 1) & 1) + (m & 3);
        int k  = 32 * (idx & 1) + k2;
        wsS[W2T_OFF + i] = (short)f2bf(W2[k * HID + j3]);
    }
    for (int i = t; i < 2048; i += STR) {          // w1t
        int tt = i >> 9, m = (i >> 5) & 15, k = i & 31;
        int j = 32 * (tt >> 1) + 8 * (m >> 2) + 4 * (tt & 1) + (m & 3);
        float v = (k < 3) ? W1[k * HID + j] : ((k == 3) ? b1[j] : 0.0f);
        wsS[W1T_OFF + i] = (short)f2bf(v);
    }
    for (int i = t; i < 1024; i += STR) {          // w3t: row m = W3[:, m&3]
        int c = i >> 6, j = i & 63;
        wsS[W3T_OFF + i] = (short)f2bf(W3[j * 4 + (c & 3)]);
    }
    if (t < 16) wsF[B3P_FLT + t] = (t < 4) ? b3[t] : 0.0f;
    else if (t >= 16 && t < 80) wsF[B2_FLT + (t - 16)] = b2[t - 16];
    for (int i = t; i < (WS_BYTES / 4) - (B2_FLT + 64); i += STR)   // zero pad
        wsF[B2_FLT + 64 + i] = 0.0f;
}

__global__ __launch_bounds__(256, 2) void nerf_reg10(
    const float* __restrict__ Kmat, const float* __restrict__ Twc,
    const float* __restrict__ aabb_min, const float* __restrict__ aabb_max,
    const short* __restrict__ ws, float* __restrict__ out) {
    // LDS: weights (loaded ONCE per block, reused ITER times) + 32 pixels'
    // ray params. NO LDS writes after the single __syncthreads -> the ITER
    // loop is race-free by construction (raw outputs routed in registers).
    __shared__ __align__(16) short wlds[WS_BYTES / 2];   // 15360 B
    __shared__ __align__(16) float pp[32][12];           // 1536 B

    const int tid  = threadIdx.x;
    const int wave = tid >> 6;
    const int lane = tid & 63;
    const int l15  = lane & 15;
    const int g    = lane >> 4;

    // ---- issue async weight copy first (latency hides under setup) ----
    {
        const char* wsb = (const char*)ws;
        char* wl = (char*)wlds;
        for (int c = wave; c < WS_BYTES / 1024; c += 4)
            gload_lds16(wsb + c * 1024 + lane * 16, wl + c * 1024);
    }

    // ---- ray setup for all ITER*8 = 32 pixels (one lane per pixel) ----
    if (tid < 32) {
        int p = blockIdx.x * 32 + tid;
        int y = p / IMG_W, x = p - y * IMG_W;
        float fx = Kmat[0], cx = Kmat[2], fy = Kmat[4], cy = Kmat[5];
        float u = (float)x + 0.5f, v = (float)y + 0.5f;
        float dcx = (u - cx) * __builtin_amdgcn_rcpf(fx);
        float dcy = (v - cy) * __builtin_amdgcn_rcpf(fy);
        float dcz = 1.0f;
        float inorm = rsqrtf(dcx * dcx + dcy * dcy + dcz * dcz);
        dcx *= inorm; dcy *= inorm; dcz *= inorm;
        float dx = Twc[0] * dcx + Twc[1] * dcy + Twc[2]  * dcz;
        float dy = Twc[4] * dcx + Twc[5] * dcy + Twc[6]  * dcz;
        float dz = Twc[8] * dcx + Twc[9] * dcy + Twc[10] * dcz;
        float ox = Twc[3], oy = Twc[7], oz = Twc[11];

        float mnx = aabb_min[0], mny = aabb_min[1], mnz = aabb_min[2];
        float mxx = aabb_max[0], mxy = aabb_max[1], mxz = aabb_max[2];
        float ivx = __builtin_amdgcn_rcpf(dx);
        float ivy = __builtin_amdgcn_rcpf(dy);
        float ivz = __builtin_amdgcn_rcpf(dz);
        float t1x = (mnx - ox) * ivx, t2x = (mxx - ox) * ivx;
        float t1y = (mny - oy) * ivy, t2y = (mxy - oy) * ivy;
        float t1z = (mnz - oz) * ivz, t2z = (mxz - oz) * ivz;
        float tnear = fmaxf(fmaxf(fminf(t1x, t2x), fminf(t1y, t2y)), fminf(t1z, t2z));
        float tfar  = fminf(fminf(fmaxf(t1x, t2x), fmaxf(t1y, t2y)), fmaxf(t1z, t2z));
        bool hit = tnear < tfar;
        float tn = hit ? tnear : 0.0f;
        float tf = hit ? tfar  : 1.0f;
        float step = (tf - tn) * (1.0f / NS);
        float iex = 2.0f * __builtin_amdgcn_rcpf(mxx - mnx);
        float iey = 2.0f * __builtin_amdgcn_rcpf(mxy - mny);
        float iez = 2.0f * __builtin_amdgcn_rcpf(mxz - mnz);
        pp[tid][0] = dx * iex;                    // Ax
        pp[tid][1] = dy * iey;                    // Ay
        pp[tid][2] = dz * iez;                    // Az
        pp[tid][3] = (ox - mnx) * iex - 1.0f;     // Bx
        pp[tid][4] = (oy - mny) * iey - 1.0f;     // By
        pp[tid][5] = (oz - mnz) * iez - 1.0f;     // Bz
        pp[tid][6] = tn;
        pp[tid][7] = step;
        pp[tid][8] = hit ? 1.0f : 0.0f;
    }
    __syncthreads();   // weights in LDS + pp visible; last LDS write in kernel

    const short* w2l = wlds + W2T_OFF;
    const short* w1l = wlds + W1T_OFF;
    const short* w3l = wlds + W3T_OFF;
    const float* bpf = reinterpret_cast<const float*>(wlds);

    const int s   = tid & 31;                // sample index within pixel
    const int lp0 = (tid >> 5) & 7;          // local pixel within octet
    const float sph = (float)s + 0.5f;

    // ---- only a2 (the full-rate L2 weights, used 8x per nt) stays resident ----
    short8 a2[8];
#pragma unroll
    for (int i = 0; i < 8; ++i)
        a2[i] = *reinterpret_cast<const short8*>(w2l + (i * 16 + l15) * 32 + 8 * g);

    // ================= ITER pixel-octets, no LDS writes =================
#pragma unroll 1
    for (int it = 0; it < ITER; ++it) {
        const int lp = it * 8 + lp0;

        float4v P0 = *reinterpret_cast<const float4v*>(&pp[lp][0]);  // Ax,Ay,Az,Bx
        float4v P1 = *reinterpret_cast<const float4v*>(&pp[lp][4]);  // By,Bz,tn,step
        float hitf = pp[lp][8];
        float step = P1[3];
        float tsv  = fmaf(step, sph, P1[2]);
        float nx = fmaf(tsv, P0[0], P0[3]);
        float ny = fmaf(tsv, P0[1], P1[0]);
        float nz = fmaf(tsv, P0[2], P1[1]);

        unsigned pd0 = cvtpk(nx, ny);
        unsigned pd1 = cvtpk(nz, 1.0f);

        // L1 B-operands for all 4 chains up front
        int u0v[4], u1v[4];
#pragma unroll
        for (int nt = 0; nt < 4; ++nt) {
            u0v[nt] = __shfl((int)pd0, 16 * nt + l15, 64);
            u1v[nt] = __shfl((int)pd1, 16 * nt + l15, 64);
        }

        // fused 3-layer MLP in registers; incremental raw-quad select.
        // Small fragments (a1/binit/a3/ci) are re-read per nt with volatile
        // ds_reads -> transient lifetime -> lower peak-live -> more waves.
        float r0 = 0.f, r1 = 0.f, r2 = 0.f, r3 = 0.f;
#pragma unroll
        for (int nt = 0; nt < 4; ++nt) {
            // issue all transient-fragment reads up front (latency hides
            // under the bi setup below; one wait before first use)
            short8 a1v[4];
#pragma unroll
            for (int t = 0; t < 4; ++t)
                a1v[t] = ldsr16nw(w1l + (t * 16 + l15) * 32 + 8 * g);
            float4v binitv[4];
#pragma unroll
            for (int uu = 0; uu < 4; ++uu)
                binitv[uu] = ldsr16fnw(bpf + B2_FLT + 32 * (uu >> 1) + 4 * (uu & 1) + 8 * g);
            short8 a30 = ldsr16nw(w3l + l15 * HID + 8 * g);
            short8 a31 = ldsr16nw(w3l + l15 * HID + 32 + 8 * g);
            float4v civ = ldsr16fnw(bpf + B3P_FLT);

            int4v bi;
            bi[0] = (g == 0) ? u0v[nt] : 0;
            bi[1] = (g == 0) ? u1v[nt] : 0;
            bi[2] = 0; bi[3] = 0;
            short8 bx = *reinterpret_cast<short8*>(&bi);

            LGKM_WAIT();   // all transient fragments now valid

            float4v c1[4];
#pragma unroll
            for (int t = 0; t < 4; ++t)
                c1[t] = __builtin_amdgcn_mfma_f32_16x16x32_bf16(
                    a1v[t], bx, (float4v){0.f, 0.f, 0.f, 0.f}, 0, 0, 0);
            short8 pa0 = packfrag(c1[0], c1[1]);
            short8 pa1 = packfrag(c1[2], c1[3]);

            float4v c2[4];
#pragma unroll
            for (int uu = 0; uu < 4; ++uu) c2[uu] = binitv[uu];
#pragma unroll
            for (int uu = 0; uu < 4; ++uu)
                c2[uu] = __builtin_amdgcn_mfma_f32_16x16x32_bf16(a2[uu * 2 + 0], pa0,
                                                                 c2[uu], 0, 0, 0);
#pragma unroll
            for (int uu = 0; uu < 4; ++uu)
                c2[uu] = __builtin_amdgcn_mfma_f32_16x16x32_bf16(a2[uu * 2 + 1], pa1,
                                                                 c2[uu], 0, 0, 0);
            short8 pb0 = packfrag(c2[0], c2[1]);
            short8 pb1 = packfrag(c2[2], c2[3]);

            float4v dv = __builtin_amdgcn_mfma_f32_16x16x32_bf16(a30, pb0, civ, 0, 0, 0);
            dv = __builtin_amdgcn_mfma_f32_16x16x32_bf16(a31, pb1, dv, 0, 0, 0);
            bool mine = (g == nt);
            r0 = mine ? dv[0] : r0;
            r1 = mine ? dv[1] : r1;
            r2 = mine ? dv[2] : r2;
            r3 = mine ? dv[3] : r3;
        }

        // volume rendering (per sample; DPP scans)
        float sigma = fmaxf(r0, 0.0f) + __logf(1.0f + __expf(-fabsf(r0)));
        float c0 = __builtin_amdgcn_rcpf(1.0f + __expf(-r1));
        float c1 = __builtin_amdgcn_rcpf(1.0f + __expf(-r2));
        float c2 = __builtin_amdgcn_rcpf(1.0f + __expf(-r3));
        float delta = (s == NS - 1) ? 0.5f * step : step;
        float sa = sigma * delta;

        float cum = scan32(sa);
        float Tprev = __expf(-(cum - sa));
        float w = Tprev * (1.0f - __expf(-sa));
        float rr = scan32(w * c0);
        float rg = scan32(w * c1);
        float rb = scan32(w * c2);

        if (s == NS - 1) {                   // lane 31/63 holds the totals
            int pix = blockIdx.x * 32 + lp;
            float alpha = 1.0f - __expf(-cum);
            float o0 = rr, o1 = rg, o2 = rb;
            if (hitf == 0.0f) { o0 = 0.0f; o1 = 0.0f; o2 = 0.0f; alpha = 0.0f; }
            out[0 * NPIX + pix] = o0;
            out[1 * NPIX + pix] = o1;
            out[2 * NPIX + pix] = o2;
            out[3 * NPIX + pix] = alpha;
        }
    }
}

extern "C" void kernel_launch(void* const* d_in, const int* in_sizes, int n_in,
                              void* d_out, int out_size, void* d_ws, size_t ws_size,
                              hipStream_t stream) {
    const float* Kmat = (const float*)d_in[0];
    const float* Twc  = (const float*)d_in[1];
    const float* amn  = (const float*)d_in[2];
    const float* amx  = (const float*)d_in[3];
    const float* W1   = (const float*)d_in[4];
    const float* b1   = (const float*)d_in[5];
    const float* W2   = (const float*)d_in[6];
    const float* b2   = (const float*)d_in[7];
    const float* W3   = (const float*)d_in[8];
    const float* b3   = (const float*)d_in[9];
    float* out = (float*)d_out;
    short* ws  = (short*)d_ws;   // 15360 B used

    prep<<<PREP_BLOCKS, 256, 0, stream>>>(W1, b1, W2, W3, b3, b2, ws);

    int blocks = NPIX * NS / 256 / ITER;   // 3,200
    nerf_reg10<<<blocks, 256, 0, stream>>>(Kmat, Twc, amn, amx, ws, out);
}

// Round 18
// 64.557 us; speedup vs baseline: 1.0509x; 1.0509x over previous
//
#include <hip/hip_runtime.h>
#include <hip/hip_bf16.h>

#define IMG_H 320
#define IMG_W 320
#define NPIX (IMG_H * IMG_W)
#define HID 64
#define NS 32
#define ITER 4   // pixel-octets per block (round-12/16 best config)

typedef __attribute__((ext_vector_type(8))) short short8;   // bf16 x8 (4 VGPR)
typedef __attribute__((ext_vector_type(4))) float float4v;
typedef __attribute__((ext_vector_type(4))) int   int4v;

// Pin a value's register class to ArchVGPR (no-op instruction-wise; round-16
// measured best-config includes these, neutral vs round-12 within noise).
#define FORCE_V(x) asm("" : "+v"(x))

// ws layout (shorts): w2t[4096] | w1t[2048] | w3t[1024] ; floats: b3pad[16] | b2[64] | zpad
#define W2T_OFF 0
#define W1T_OFF 4096
#define W3T_OFF (4096 + 2048)
#define B3P_FLT 3584            // float index of b3pad (byte 14336)
#define B2_FLT  3600            // float index of b2 copy (byte 14400)
#define WS_BYTES 15360
#define PREP_BLOCKS 8

__device__ __forceinline__ unsigned f2bf(float f) {   // prep kernel only (cold)
    __hip_bfloat16 b = __float2bfloat16(f);
    return (unsigned)*reinterpret_cast<unsigned short*>(&b);
}

// HW packed f32->bf16 (RNE): lo16 = bf16(lo), hi16 = bf16(hi). One VALU op.
__device__ __forceinline__ unsigned cvtpk(float lo, float hi) {
    unsigned r;
    asm("v_cvt_pk_bf16_f32 %0, %1, %2" : "=v"(r) : "v"(lo), "v"(hi));
    return r;
}

// relu + pack two D-fragments (lo-half, hi-half) into the next layer's B-fragment.
__device__ __forceinline__ short8 packfrag(float4v lo, float4v hi) {
    int4v p;
    p[0] = (int)cvtpk(fmaxf(lo[0], 0.f), fmaxf(lo[1], 0.f));
    p[1] = (int)cvtpk(fmaxf(lo[2], 0.f), fmaxf(lo[3], 0.f));
    p[2] = (int)cvtpk(fmaxf(hi[0], 0.f), fmaxf(hi[1], 0.f));
    p[3] = (int)cvtpk(fmaxf(hi[2], 0.f), fmaxf(hi[3], 0.f));
    return *reinterpret_cast<short8*>(&p);
}

// DPP add helper + 32-lane inclusive scan (pure VALU, no LDS)
template <int CTRL, int RMASK>
__device__ __forceinline__ float dppadd(float x) {
    int s = __builtin_amdgcn_update_dpp(0, __float_as_int(x), CTRL, RMASK, 0xF, true);
    return x + __int_as_float(s);
}
__device__ __forceinline__ float scan32(float x) {
    x = dppadd<0x111, 0xF>(x);   // row_shr:1
    x = dppadd<0x112, 0xF>(x);   // row_shr:2
    x = dppadd<0x114, 0xF>(x);   // row_shr:4
    x = dppadd<0x118, 0xF>(x);   // row_shr:8
    x = dppadd<0x142, 0xA>(x);   // row_bcast:15 into rows 1,3
    return x;
}

// async global->LDS, 16B per lane (dest = uniform base + lane*16)
__device__ __forceinline__ void gload_lds16(const void* g, void* l) {
    __builtin_amdgcn_global_load_lds(
        (const __attribute__((address_space(1))) unsigned int*)g,
        (__attribute__((address_space(3))) unsigned int*)l, 16, 0, 0);
}

// Layout-fused weight tables (round-8 permutation for w1t/w2t; w3t rows
// replicated so every lane group receives the full raw quad -> register-only
// routing, race-free ITER loop).
__global__ __launch_bounds__(256) void prep(const float* __restrict__ W1,
                                            const float* __restrict__ b1,
                                            const float* __restrict__ W2,
                                            const float* __restrict__ W3,
                                            const float* __restrict__ b3,
                                            const float* __restrict__ b2,
                                            short* __restrict__ wsS) {
    int t = blockIdx.x * 256 + threadIdx.x;
    const int STR = 256 * PREP_BLOCKS;
    float* wsF = reinterpret_cast<float*>(wsS);
    for (int i = t; i < 4096; i += STR) {          // w2t
        int idx = i >> 9, m = (i >> 5) & 15, k2 = i & 31;
        int j3 = 32 * (idx >> 2) + 8 * (m >> 2) + 4 * ((idx >> 1) & 1) + (m & 3);
        int k  = 32 * (idx & 1) + k2;
        wsS[W2T_OFF + i] = (short)f2bf(W2[k * HID + j3]);
    }
    for (int i = t; i < 2048; i += STR) {          // w1t
        int tt = i >> 9, m = (i >> 5) & 15, k = i & 31;
        int j = 32 * (tt >> 1) + 8 * (m >> 2) + 4 * (tt & 1) + (m & 3);
        float v = (k < 3) ? W1[k * HID + j] : ((k == 3) ? b1[j] : 0.0f);
        wsS[W1T_OFF + i] = (short)f2bf(v);
    }
    for (int i = t; i < 1024; i += STR) {          // w3t: row m = W3[:, m&3]
        int c = i >> 6, j = i & 63;
        wsS[W3T_OFF + i] = (short)f2bf(W3[j * 4 + (c & 3)]);
    }
    if (t < 16) wsF[B3P_FLT + t] = (t < 4) ? b3[t] : 0.0f;
    else if (t >= 16 && t < 80) wsF[B2_FLT + (t - 16)] = b2[t - 16];
    for (int i = t; i < (WS_BYTES / 4) - (B2_FLT + 64); i += STR)   // zero pad
        wsF[B2_FLT + 64 + i] = 0.0f;
}

__global__ __launch_bounds__(256, 2) void nerf_reg9(
    const float* __restrict__ Kmat, const float* __restrict__ Twc,
    const float* __restrict__ aabb_min, const float* __restrict__ aabb_max,
    const short* __restrict__ ws, float* __restrict__ out) {
    // LDS: weights (loaded ONCE per block, reused ITER times) + 32 pixels'
    // ray params. NO LDS writes after the single __syncthreads -> the ITER
    // loop is race-free by construction (raw outputs routed in registers).
    __shared__ __align__(16) short wlds[WS_BYTES / 2];   // 15360 B
    __shared__ __align__(16) float pp[32][12];           // 1536 B

    const int tid  = threadIdx.x;
    const int wave = tid >> 6;
    const int lane = tid & 63;
    const int l15  = lane & 15;
    const int g    = lane >> 4;

    // ---- issue async weight copy first (latency hides under setup) ----
    {
        const char* wsb = (const char*)ws;
        char* wl = (char*)wlds;
        for (int c = wave; c < WS_BYTES / 1024; c += 4)
            gload_lds16(wsb + c * 1024 + lane * 16, wl + c * 1024);
    }

    // ---- ray setup for all ITER*8 = 32 pixels (one lane per pixel) ----
    if (tid < 32) {
        int p = blockIdx.x * 32 + tid;
        int y = p / IMG_W, x = p - y * IMG_W;
        float fx = Kmat[0], cx = Kmat[2], fy = Kmat[4], cy = Kmat[5];
        float u = (float)x + 0.5f, v = (float)y + 0.5f;
        float dcx = (u - cx) * __builtin_amdgcn_rcpf(fx);
        float dcy = (v - cy) * __builtin_amdgcn_rcpf(fy);
        float dcz = 1.0f;
        float inorm = rsqrtf(dcx * dcx + dcy * dcy + dcz * dcz);
        dcx *= inorm; dcy *= inorm; dcz *= inorm;
        float dx = Twc[0] * dcx + Twc[1] * dcy + Twc[2]  * dcz;
        float dy = Twc[4] * dcx + Twc[5] * dcy + Twc[6]  * dcz;
        float dz = Twc[8] * dcx + Twc[9] * dcy + Twc[10] * dcz;
        float ox = Twc[3], oy = Twc[7], oz = Twc[11];

        float mnx = aabb_min[0], mny = aabb_min[1], mnz = aabb_min[2];
        float mxx = aabb_max[0], mxy = aabb_max[1], mxz = aabb_max[2];
        float ivx = __builtin_amdgcn_rcpf(dx);
        float ivy = __builtin_amdgcn_rcpf(dy);
        float ivz = __builtin_amdgcn_rcpf(dz);
        float t1x = (mnx - ox) * ivx, t2x = (mxx - ox) * ivx;
        float t1y = (mny - oy) * ivy, t2y = (mxy - oy) * ivy;
        float t1z = (mnz - oz) * ivz, t2z = (mxz - oz) * ivz;
        float tnear = fmaxf(fmaxf(fminf(t1x, t2x), fminf(t1y, t2y)), fminf(t1z, t2z));
        float tfar  = fminf(fminf(fmaxf(t1x, t2x), fmaxf(t1y, t2y)), fmaxf(t1z, t2z));
        bool hit = tnear < tfar;
        float tn = hit ? tnear : 0.0f;
        float tf = hit ? tfar  : 1.0f;
        float step = (tf - tn) * (1.0f / NS);
        float iex = 2.0f * __builtin_amdgcn_rcpf(mxx - mnx);
        float iey = 2.0f * __builtin_amdgcn_rcpf(mxy - mny);
        float iez = 2.0f * __builtin_amdgcn_rcpf(mxz - mnz);
        pp[tid][0] = dx * iex;                    // Ax
        pp[tid][1] = dy * iey;                    // Ay
        pp[tid][2] = dz * iez;                    // Az
        pp[tid][3] = (ox - mnx) * iex - 1.0f;     // Bx
        pp[tid][4] = (oy - mny) * iey - 1.0f;     // By
        pp[tid][5] = (oz - mnz) * iez - 1.0f;     // Bz
        pp[tid][6] = tn;
        pp[tid][7] = step;
        pp[tid][8] = hit ? 1.0f : 0.0f;
    }
    __syncthreads();   // weights in LDS + pp visible; last LDS write in kernel

    const short* w2l = wlds + W2T_OFF;
    const short* w1l = wlds + W1T_OFF;
    const short* w3l = wlds + W3T_OFF;
    const float* bpf = reinterpret_cast<const float*>(wlds);

    const int s   = tid & 31;                // sample index within pixel
    const int lp0 = (tid >> 5) & 7;          // local pixel within octet
    const float sph = (float)s + 0.5f;

    // ---- weight fragments from LDS, pinned to ArchVGPRs ----
    short8 a1[4];
#pragma unroll
    for (int t = 0; t < 4; ++t) {
        a1[t] = *reinterpret_cast<const short8*>(w1l + (t * 16 + l15) * 32 + 8 * g);
        FORCE_V(a1[t]);
    }
    short8 a2[8];
#pragma unroll
    for (int i = 0; i < 8; ++i) {
        a2[i] = *reinterpret_cast<const short8*>(w2l + (i * 16 + l15) * 32 + 8 * g);
        FORCE_V(a2[i]);
    }
    short8 a3[2];
#pragma unroll
    for (int T3 = 0; T3 < 2; ++T3) {
        a3[T3] = *reinterpret_cast<const short8*>(w3l + l15 * HID + 32 * T3 + 8 * g);
        FORCE_V(a3[T3]);
    }
    float4v binit[4];
#pragma unroll
    for (int uu = 0; uu < 4; ++uu) {
        binit[uu] = *reinterpret_cast<const float4v*>(
            bpf + B2_FLT + 32 * (uu >> 1) + 4 * (uu & 1) + 8 * g);
        FORCE_V(binit[uu]);
    }
    // replicated-w3t C-init: b3[r] for all lanes (b3pad[0..3] = b3)
    float4v ci = *reinterpret_cast<const float4v*>(bpf + B3P_FLT);
    FORCE_V(ci);

    // ================= ITER pixel-octets, no LDS writes =================
#pragma unroll 1
    for (int it = 0; it < ITER; ++it) {
        const int lp = it * 8 + lp0;

        float4v P0 = *reinterpret_cast<const float4v*>(&pp[lp][0]);  // Ax,Ay,Az,Bx
        float4v P1 = *reinterpret_cast<const float4v*>(&pp[lp][4]);  // By,Bz,tn,step
        float hitf = pp[lp][8];
        float step = P1[3];
        float tsv  = fmaf(step, sph, P1[2]);
        float nx = fmaf(tsv, P0[0], P0[3]);
        float ny = fmaf(tsv, P0[1], P1[0]);
        float nz = fmaf(tsv, P0[2], P1[1]);

        unsigned pd0 = cvtpk(nx, ny);
        unsigned pd1 = cvtpk(nz, 1.0f);

        // L1 B-operands for all 4 chains up front
        int u0v[4], u1v[4];
#pragma unroll
        for (int nt = 0; nt < 4; ++nt) {
            u0v[nt] = __shfl((int)pd0, 16 * nt + l15, 64);
            u1v[nt] = __shfl((int)pd1, 16 * nt + l15, 64);
        }

        // fused 3-layer MLP in registers; incremental raw-quad select
        float r0 = 0.f, r1 = 0.f, r2 = 0.f, r3 = 0.f;
#pragma unroll
        for (int nt = 0; nt < 4; ++nt) {
            int4v bi;
            bi[0] = (g == 0) ? u0v[nt] : 0;
            bi[1] = (g == 0) ? u1v[nt] : 0;
            bi[2] = 0; bi[3] = 0;
            short8 bx = *reinterpret_cast<short8*>(&bi);

            float4v c1[4];
#pragma unroll
            for (int t = 0; t < 4; ++t) {
                c1[t] = __builtin_amdgcn_mfma_f32_16x16x32_bf16(
                    a1[t], bx, (float4v){0.f, 0.f, 0.f, 0.f}, 0, 0, 0);
                FORCE_V(c1[t]);   // D in ArchVGPR -> packfrag reads are plain VALU
            }
            short8 pa0 = packfrag(c1[0], c1[1]);
            short8 pa1 = packfrag(c1[2], c1[3]);

            float4v c2[4];
#pragma unroll
            for (int uu = 0; uu < 4; ++uu) c2[uu] = binit[uu];
#pragma unroll
            for (int uu = 0; uu < 4; ++uu)
                c2[uu] = __builtin_amdgcn_mfma_f32_16x16x32_bf16(a2[uu * 2 + 0], pa0,
                                                                 c2[uu], 0, 0, 0);
#pragma unroll
            for (int uu = 0; uu < 4; ++uu) {
                c2[uu] = __builtin_amdgcn_mfma_f32_16x16x32_bf16(a2[uu * 2 + 1], pa1,
                                                                 c2[uu], 0, 0, 0);
                FORCE_V(c2[uu]);
            }
            short8 pb0 = packfrag(c2[0], c2[1]);
            short8 pb1 = packfrag(c2[2], c2[3]);

            float4v dv = __builtin_amdgcn_mfma_f32_16x16x32_bf16(a3[0], pb0, ci, 0, 0, 0);
            dv = __builtin_amdgcn_mfma_f32_16x16x32_bf16(a3[1], pb1, dv, 0, 0, 0);
            FORCE_V(dv);
            bool mine = (g == nt);
            r0 = mine ? dv[0] : r0;
            r1 = mine ? dv[1] : r1;
            r2 = mine ? dv[2] : r2;
            r3 = mine ? dv[3] : r3;
        }

        // volume rendering (per sample; DPP scans)
        float sigma = fmaxf(r0, 0.0f) + __logf(1.0f + __expf(-fabsf(r0)));
        float c0 = __builtin_amdgcn_rcpf(1.0f + __expf(-r1));
        float c1 = __builtin_amdgcn_rcpf(1.0f + __expf(-r2));
        float c2 = __builtin_amdgcn_rcpf(1.0f + __expf(-r3));
        float delta = (s == NS - 1) ? 0.5f * step : step;
        float sa = sigma * delta;

        float cum = scan32(sa);
        float Tprev = __expf(-(cum - sa));
        float w = Tprev * (1.0f - __expf(-sa));
        float rr = scan32(w * c0);
        float rg = scan32(w * c1);
        float rb = scan32(w * c2);

        if (s == NS - 1) {                   // lane 31/63 holds the totals
            int pix = blockIdx.x * 32 + lp;
            float alpha = 1.0f - __expf(-cum);
            float o0 = rr, o1 = rg, o2 = rb;
            if (hitf == 0.0f) { o0 = 0.0f; o1 = 0.0f; o2 = 0.0f; alpha = 0.0f; }
            out[0 * NPIX + pix] = o0;
            out[1 * NPIX + pix] = o1;
            out[2 * NPIX + pix] = o2;
            out[3 * NPIX + pix] = alpha;
        }
    }
}

extern "C" void kernel_launch(void* const* d_in, const int* in_sizes, int n_in,
                              void* d_out, int out_size, void* d_ws, size_t ws_size,
                              hipStream_t stream) {
    const float* Kmat = (const float*)d_in[0];
    const float* Twc  = (const float*)d_in[1];
    const float* amn  = (const float*)d_in[2];
    const float* amx  = (const float*)d_in[3];
    const float* W1   = (const float*)d_in[4];
    const float* b1   = (const float*)d_in[5];
    const float* W2   = (const float*)d_in[6];
    const float* b2   = (const float*)d_in[7];
    const float* W3   = (const float*)d_in[8];
    const float* b3   = (const float*)d_in[9];
    float* out = (float*)d_out;
    short* ws  = (short*)d_ws;   // 15360 B used

    prep<<<PREP_BLOCKS, 256, 0, stream>>>(W1, b1, W2, W3, b3, b2, ws);

    int blocks = NPIX * NS / 256 / ITER;   // 3,200
    nerf_reg9<<<blocks, 256, 0, stream>>>(Kmat, Twc, amn, amx, ws, out);
}